// Round 4
// baseline (637.310 us; speedup 1.0000x reference)
//
#include <hip/hip_runtime.h>

// DeformableGCN: 3x mean-smoothing + 2x attention-weighted GCN conv.
// CSR-by-dst, node-level transforms, wave-per-dst-node gathers.
// R1: two-level scan. R2: float4 multi-edge gathers. R4: bucketed CSR build
// (dense writes, 52MB->~10MB write traffic) + deeper gather MLP (16 edges
// in flight per wave).

#define BUCKET_SHIFT 7
#define BUCKET_CAP 4000

// Pass A: degree count + bucket append (dense 8B writes per bucket).
__global__ void bucket_kernel(const int* __restrict__ src, const int* __restrict__ dst,
                              int* __restrict__ deg, int* __restrict__ bcur,
                              int2* __restrict__ temp, int E) {
    int e = blockIdx.x * blockDim.x + threadIdx.x;
    if (e >= E) return;
    int d = dst[e];
    atomicAdd(&deg[d], 1);
    int b = d >> BUCKET_SHIFT;
    int slot = atomicAdd(&bcur[b], 1);
    temp[(size_t)b * BUCKET_CAP + slot] = make_int2(src[e], d);
}

__global__ void block_sum_kernel(const int* __restrict__ deg, int* __restrict__ blockSums, int N) {
    __shared__ int sh[256];
    int i = blockIdx.x * 256 + threadIdx.x;
    int v = (i < N) ? deg[i] : 0;
    sh[threadIdx.x] = v;
    __syncthreads();
    for (int off = 128; off > 0; off >>= 1) {
        if (threadIdx.x < off) sh[threadIdx.x] += sh[threadIdx.x + off];
        __syncthreads();
    }
    if (threadIdx.x == 0) blockSums[blockIdx.x] = sh[0];
}

__global__ void scan_sums_kernel(int* __restrict__ blockSums, int* __restrict__ row_ptr_N, int B) {
    __shared__ int sh[1024];
    int t = threadIdx.x;
    int v = (t < B) ? blockSums[t] : 0;
    sh[t] = v;
    __syncthreads();
    for (int off = 1; off < 1024; off <<= 1) {
        int u = (t >= off) ? sh[t - off] : 0;
        __syncthreads();
        sh[t] += u;
        __syncthreads();
    }
    if (t < B) blockSums[t] = sh[t] - v;
    if (t == 1023) row_ptr_N[0] = sh[1023];
}

__global__ void write_rowptr_kernel(const int* __restrict__ deg, const int* __restrict__ blockOffs,
                                    int* __restrict__ row_ptr, int* __restrict__ cursor, int N) {
    __shared__ int sh[256];
    int i = blockIdx.x * 256 + threadIdx.x;
    int v = (i < N) ? deg[i] : 0;
    sh[threadIdx.x] = v;
    __syncthreads();
    for (int off = 1; off < 256; off <<= 1) {
        int u = (threadIdx.x >= off) ? sh[threadIdx.x - off] : 0;
        __syncthreads();
        sh[threadIdx.x] += u;
        __syncthreads();
    }
    if (i < N) {
        int excl = blockOffs[blockIdx.x] + sh[threadIdx.x] - v;
        row_ptr[i] = excl;
        cursor[i] = excl;
    }
}

// Pass B: one block per bucket; final scatter stays within the bucket's
// ~8KB src_idx window (dense, L2-resident).
__global__ void bucket_scatter_kernel(const int2* __restrict__ temp, const int* __restrict__ bcnt,
                                      int* __restrict__ cursor, int* __restrict__ src_idx) {
    int b = blockIdx.x;
    int cnt = bcnt[b];
    const int2* tb = temp + (size_t)b * BUCKET_CAP;
    for (int i = threadIdx.x; i < cnt; i += blockDim.x) {
        int2 p = tb[i];
        int slot = atomicAdd(&cursor[p.y], 1);
        src_idx[slot] = p.x;
    }
}

// Mean aggregation, one wave per dst node. 4 lane-groups x 16 lanes; each
// group handles 4 edges per iteration (16 edges in flight per wave).
__global__ void agg_mean_kernel(const float* __restrict__ h, const int* __restrict__ row_ptr,
                                const int* __restrict__ src_idx,
                                float* __restrict__ h_out, int N) {
    int wid = (blockIdx.x * blockDim.x + threadIdx.x) >> 6;
    int lane = threadIdx.x & 63;
    if (wid >= N) return;
    int beg = row_ptr[wid], end = row_ptr[wid + 1];
    int j = lane >> 4;
    int f = lane & 15;
    float4 a0 = make_float4(0.f, 0.f, 0.f, 0.f);
    float4 a1 = make_float4(0.f, 0.f, 0.f, 0.f);
    float4 a2 = make_float4(0.f, 0.f, 0.f, 0.f);
    float4 a3 = make_float4(0.f, 0.f, 0.f, 0.f);
    for (int e = beg + 4 * j; e < end; e += 16) {
        int rem = end - e;
        int s0 = src_idx[e];
        float4 v0 = *((const float4*)(h + (size_t)s0 * 64) + f);
        a0.x += v0.x; a0.y += v0.y; a0.z += v0.z; a0.w += v0.w;
        if (rem > 1) {
            int s1 = src_idx[e + 1];
            float4 v1 = *((const float4*)(h + (size_t)s1 * 64) + f);
            a1.x += v1.x; a1.y += v1.y; a1.z += v1.z; a1.w += v1.w;
        }
        if (rem > 2) {
            int s2 = src_idx[e + 2];
            float4 v2 = *((const float4*)(h + (size_t)s2 * 64) + f);
            a2.x += v2.x; a2.y += v2.y; a2.z += v2.z; a2.w += v2.w;
        }
        if (rem > 3) {
            int s3 = src_idx[e + 3];
            float4 v3 = *((const float4*)(h + (size_t)s3 * 64) + f);
            a3.x += v3.x; a3.y += v3.y; a3.z += v3.z; a3.w += v3.w;
        }
    }
    a0.x += a1.x + a2.x + a3.x; a0.y += a1.y + a2.y + a3.y;
    a0.z += a1.z + a2.z + a3.z; a0.w += a1.w + a2.w + a3.w;
    a0.x += __shfl_down(a0.x, 32, 64); a0.y += __shfl_down(a0.y, 32, 64);
    a0.z += __shfl_down(a0.z, 32, 64); a0.w += __shfl_down(a0.w, 32, 64);
    a0.x += __shfl_down(a0.x, 16, 64); a0.y += __shfl_down(a0.y, 16, 64);
    a0.z += __shfl_down(a0.z, 16, 64); a0.w += __shfl_down(a0.w, 16, 64);
    if (lane < 16) {
        int d = end - beg;
        float inv = d > 0 ? 1.f / (float)d : 0.f;
        float4 o; o.x = a0.x * inv; o.y = a0.y * inv; o.z = a0.z * inv; o.w = a0.w * inv;
        *((float4*)(h_out + (size_t)wid * 64) + lane) = o;
    }
}

// Conv1 transform: xs = (x+h1+h2+h3)/4 folded in. z1 = xs@W_lin1, a1/a2 dots.
__global__ void xform1_kernel(const float* __restrict__ x, const float* __restrict__ hA,
                              const float* __restrict__ hB, const float* __restrict__ hC,
                              const float* __restrict__ W_lin1, const float* __restrict__ W_att1,
                              float* __restrict__ z1, float* __restrict__ a1, float* __restrict__ a2,
                              int N) {
    __shared__ float row[4][64];
    int wib = threadIdx.x >> 6;
    int lane = threadIdx.x & 63;
    int n = blockIdx.x * 4 + wib;
    int nc = n < N ? n : N - 1;
    size_t idx = (size_t)nc * 64 + lane;
    float xv = (x[idx] + hA[idx] + hB[idx] + hC[idx]) * 0.25f;
    row[wib][lane] = xv;
    __syncthreads();
    float p1 = xv * W_att1[lane];
    float p2 = xv * W_att1[64 + lane];
    for (int off = 32; off > 0; off >>= 1) {
        p1 += __shfl_down(p1, off, 64);
        p2 += __shfl_down(p2, off, 64);
    }
    float acc = 0.f;
    #pragma unroll
    for (int k = 0; k < 64; ++k) acc += row[wib][k] * W_lin1[k * 64 + lane];
    if (n < N) {
        z1[(size_t)n * 64 + lane] = acc;
        if (lane == 0) { a1[n] = p1; a2[n] = p2; }
    }
}

__global__ void xform2_kernel(const float* __restrict__ h1, const float* __restrict__ W_lin2,
                              const float* __restrict__ W_att2,
                              float* __restrict__ z2, float* __restrict__ a1, float* __restrict__ a2,
                              int N) {
    __shared__ float row[4][64];
    int wib = threadIdx.x >> 6;
    int lane = threadIdx.x & 63;
    int n = blockIdx.x * 4 + wib;
    int nc = n < N ? n : N - 1;
    float hv = h1[(size_t)nc * 64 + lane];
    row[wib][lane] = hv;
    __syncthreads();
    float p1 = hv * W_att2[lane];
    float p2 = hv * W_att2[64 + lane];
    for (int off = 32; off > 0; off >>= 1) {
        p1 += __shfl_down(p1, off, 64);
        p2 += __shfl_down(p2, off, 64);
    }
    float acc = 0.f;
    if (lane < 32) {
        #pragma unroll
        for (int k = 0; k < 64; ++k) acc += row[wib][k] * W_lin2[k * 32 + lane];
    }
    if (n < N) {
        if (lane < 32) z2[(size_t)n * 32 + lane] = acc;
        if (lane == 0) { a1[n] = p1; a2[n] = p2; }
    }
}

// Conv1 aggregation (D=64): 4 lane-groups x 16 lanes, 16 edges in flight,
// per-edge leaky score; writes relu(sum).
__global__ void agg_conv64_kernel(const float* __restrict__ z, const float* __restrict__ a1v,
                                  const float* __restrict__ a2v, const float* __restrict__ b_att,
                                  const int* __restrict__ row_ptr, const int* __restrict__ src_idx,
                                  float* __restrict__ outp, int N) {
    int wid = (blockIdx.x * blockDim.x + threadIdx.x) >> 6;
    int lane = threadIdx.x & 63;
    if (wid >= N) return;
    float ad = a2v[wid] + b_att[0];
    int beg = row_ptr[wid], end = row_ptr[wid + 1];
    int j = lane >> 4;
    int f = lane & 15;
    float4 a0 = make_float4(0.f, 0.f, 0.f, 0.f);
    float4 a1 = make_float4(0.f, 0.f, 0.f, 0.f);
    float4 a2 = make_float4(0.f, 0.f, 0.f, 0.f);
    float4 a3 = make_float4(0.f, 0.f, 0.f, 0.f);
    for (int e = beg + 4 * j; e < end; e += 16) {
        int rem = end - e;
        int s0 = src_idx[e];
        float sc0 = a1v[s0] + ad; sc0 = sc0 > 0.f ? sc0 : 0.01f * sc0;
        float4 v0 = *((const float4*)(z + (size_t)s0 * 64) + f);
        a0.x += sc0 * v0.x; a0.y += sc0 * v0.y; a0.z += sc0 * v0.z; a0.w += sc0 * v0.w;
        if (rem > 1) {
            int s1 = src_idx[e + 1];
            float sc1 = a1v[s1] + ad; sc1 = sc1 > 0.f ? sc1 : 0.01f * sc1;
            float4 v1 = *((const float4*)(z + (size_t)s1 * 64) + f);
            a1.x += sc1 * v1.x; a1.y += sc1 * v1.y; a1.z += sc1 * v1.z; a1.w += sc1 * v1.w;
        }
        if (rem > 2) {
            int s2 = src_idx[e + 2];
            float sc2 = a1v[s2] + ad; sc2 = sc2 > 0.f ? sc2 : 0.01f * sc2;
            float4 v2 = *((const float4*)(z + (size_t)s2 * 64) + f);
            a2.x += sc2 * v2.x; a2.y += sc2 * v2.y; a2.z += sc2 * v2.z; a2.w += sc2 * v2.w;
        }
        if (rem > 3) {
            int s3 = src_idx[e + 3];
            float sc3 = a1v[s3] + ad; sc3 = sc3 > 0.f ? sc3 : 0.01f * sc3;
            float4 v3 = *((const float4*)(z + (size_t)s3 * 64) + f);
            a3.x += sc3 * v3.x; a3.y += sc3 * v3.y; a3.z += sc3 * v3.z; a3.w += sc3 * v3.w;
        }
    }
    a0.x += a1.x + a2.x + a3.x; a0.y += a1.y + a2.y + a3.y;
    a0.z += a1.z + a2.z + a3.z; a0.w += a1.w + a2.w + a3.w;
    a0.x += __shfl_down(a0.x, 32, 64); a0.y += __shfl_down(a0.y, 32, 64);
    a0.z += __shfl_down(a0.z, 32, 64); a0.w += __shfl_down(a0.w, 32, 64);
    a0.x += __shfl_down(a0.x, 16, 64); a0.y += __shfl_down(a0.y, 16, 64);
    a0.z += __shfl_down(a0.z, 16, 64); a0.w += __shfl_down(a0.w, 16, 64);
    if (lane < 16) {
        float4 o;
        o.x = fmaxf(a0.x, 0.f); o.y = fmaxf(a0.y, 0.f);
        o.z = fmaxf(a0.z, 0.f); o.w = fmaxf(a0.w, 0.f);
        *((float4*)(outp + (size_t)wid * 64) + lane) = o;
    }
}

// Conv2 aggregation (D=32): 8 lane-groups x 8 lanes, 2 edges per group per
// iteration (16 in flight).
__global__ void agg_conv32_kernel(const float* __restrict__ z, const float* __restrict__ a1v,
                                  const float* __restrict__ a2v, const float* __restrict__ b_att,
                                  const int* __restrict__ row_ptr, const int* __restrict__ src_idx,
                                  float* __restrict__ outp, int N) {
    int wid = (blockIdx.x * blockDim.x + threadIdx.x) >> 6;
    int lane = threadIdx.x & 63;
    if (wid >= N) return;
    float ad = a2v[wid] + b_att[0];
    int beg = row_ptr[wid], end = row_ptr[wid + 1];
    int j = lane >> 3;
    int f = lane & 7;
    float4 a0 = make_float4(0.f, 0.f, 0.f, 0.f);
    float4 a1 = make_float4(0.f, 0.f, 0.f, 0.f);
    for (int e = beg + 2 * j; e < end; e += 16) {
        int s0 = src_idx[e];
        float sc0 = a1v[s0] + ad; sc0 = sc0 > 0.f ? sc0 : 0.01f * sc0;
        float4 v0 = *((const float4*)(z + (size_t)s0 * 32) + f);
        a0.x += sc0 * v0.x; a0.y += sc0 * v0.y; a0.z += sc0 * v0.z; a0.w += sc0 * v0.w;
        if (e + 1 < end) {
            int s1 = src_idx[e + 1];
            float sc1 = a1v[s1] + ad; sc1 = sc1 > 0.f ? sc1 : 0.01f * sc1;
            float4 v1 = *((const float4*)(z + (size_t)s1 * 32) + f);
            a1.x += sc1 * v1.x; a1.y += sc1 * v1.y; a1.z += sc1 * v1.z; a1.w += sc1 * v1.w;
        }
    }
    a0.x += a1.x; a0.y += a1.y; a0.z += a1.z; a0.w += a1.w;
    a0.x += __shfl_down(a0.x, 32, 64); a0.y += __shfl_down(a0.y, 32, 64);
    a0.z += __shfl_down(a0.z, 32, 64); a0.w += __shfl_down(a0.w, 32, 64);
    a0.x += __shfl_down(a0.x, 16, 64); a0.y += __shfl_down(a0.y, 16, 64);
    a0.z += __shfl_down(a0.z, 16, 64); a0.w += __shfl_down(a0.w, 16, 64);
    a0.x += __shfl_down(a0.x, 8, 64);  a0.y += __shfl_down(a0.y, 8, 64);
    a0.z += __shfl_down(a0.z, 8, 64);  a0.w += __shfl_down(a0.w, 8, 64);
    if (lane < 8) {
        *((float4*)(outp + (size_t)wid * 32) + lane) = a0;
    }
}

extern "C" void kernel_launch(void* const* d_in, const int* in_sizes, int n_in,
                              void* d_out, int out_size, void* d_ws, size_t ws_size,
                              hipStream_t stream) {
    const float* x      = (const float*)d_in[0];
    const int*   ei     = (const int*)d_in[1];
    const float* W_att1 = (const float*)d_in[2];
    const float* b_att1 = (const float*)d_in[3];
    const float* W_lin1 = (const float*)d_in[4];
    const float* W_att2 = (const float*)d_in[5];
    const float* b_att2 = (const float*)d_in[6];
    const float* W_lin2 = (const float*)d_in[7];
    float* out = (float*)d_out;

    int N = in_sizes[0] / 64;
    int E = in_sizes[1] / 2;
    const int* src = ei;
    const int* dst = ei + E;
    int NB = (N + (1 << BUCKET_SHIFT) - 1) >> BUCKET_SHIFT;   // 391 for N=50k

    char* ws = (char*)d_ws;
    size_t off = 0;
    auto alloc = [&](size_t bytes) -> void* {
        void* p = ws + off;
        off += (bytes + 255) & ~(size_t)255;
        return p;
    };
    int*   deg       = (int*)alloc((size_t)N * 4);
    int*   row_ptr   = (int*)alloc((size_t)(N + 1) * 4);
    int*   cursor    = (int*)alloc((size_t)N * 4);
    int*   src_idx   = (int*)alloc((size_t)E * 4);
    int*   blockSums = (int*)alloc((size_t)1024 * 4);
    int*   bcur      = (int*)alloc((size_t)NB * 4);
    float* bufA      = (float*)alloc((size_t)N * 64 * 4);   // h1
    float* bufB      = (float*)alloc((size_t)N * 64 * 4);   // h2
    float* bufC      = (float*)alloc((size_t)N * 64 * 4);   // h3
    float* bufD      = (float*)alloc((size_t)N * 64 * 4);   // temp buckets, then z1/z2
    float* a1        = (float*)alloc((size_t)N * 4);
    float* a2        = (float*)alloc((size_t)N * 4);
    float* a1b       = (float*)alloc((size_t)N * 4);
    float* a2b       = (float*)alloc((size_t)N * 4);
    int2* temp = (int2*)bufD;   // NB*BUCKET_CAP int2 = 12.5MB <= N*64*4 = 12.8MB

    const int tb = 256;
    hipMemsetAsync(deg, 0, (size_t)N * 4, stream);
    hipMemsetAsync(bcur, 0, (size_t)NB * 4, stream);

    bucket_kernel<<<(E + tb - 1) / tb, tb, 0, stream>>>(src, dst, deg, bcur, temp, E);

    int B = (N + 255) / 256;
    block_sum_kernel<<<B, 256, 0, stream>>>(deg, blockSums, N);
    scan_sums_kernel<<<1, 1024, 0, stream>>>(blockSums, row_ptr + N, B);
    write_rowptr_kernel<<<B, 256, 0, stream>>>(deg, blockSums, row_ptr, cursor, N);

    bucket_scatter_kernel<<<NB, 256, 0, stream>>>(temp, bcur, cursor, src_idx);

    int aggBlocks = (N * 64 + tb - 1) / tb;   // one wave per node
    agg_mean_kernel<<<aggBlocks, tb, 0, stream>>>(x,    row_ptr, src_idx, bufA, N);
    agg_mean_kernel<<<aggBlocks, tb, 0, stream>>>(bufA, row_ptr, src_idx, bufB, N);
    agg_mean_kernel<<<aggBlocks, tb, 0, stream>>>(bufB, row_ptr, src_idx, bufC, N);

    int xfBlocks = (N + 3) / 4;
    // z1 -> bufD (temp no longer needed), h1 -> bufA
    xform1_kernel<<<xfBlocks, 256, 0, stream>>>(x, bufA, bufB, bufC, W_lin1, W_att1,
                                                bufD, a1, a2, N);
    agg_conv64_kernel<<<aggBlocks, tb, 0, stream>>>(bufD, a1, a2, b_att1, row_ptr, src_idx,
                                                    bufA, N);
    // z2 -> bufB
    xform2_kernel<<<xfBlocks, 256, 0, stream>>>(bufA, W_lin2, W_att2, bufB, a1b, a2b, N);
    agg_conv32_kernel<<<aggBlocks, tb, 0, stream>>>(bufB, a1b, a2b, b_att2, row_ptr, src_idx,
                                                    out, N);
}

// Round 5
// 366.134 us; speedup vs baseline: 1.7406x; 1.7406x over previous
//
#include <hip/hip_runtime.h>

// DeformableGCN: 3x mean-smoothing + 2x attention-weighted GCN conv.
// CSR-by-dst, node-level transforms, wave-per-dst-node gathers.
// R1: two-level scan. R2/R3: float4 multi-edge gathers (16 edges in flight).
// R4 bucketing REVERTED (atomic-append interleaves XCDs on shared lines ->
// 61MB writes + cursor contention). R5: uint16 src_idx (N<65536) and fp16
// storage for gathered intermediates (h1/h2/h3, z1) -> ~40% less gather
// traffic; accumulate fp32, z2/out stay fp32 for absmax headroom.

typedef __attribute__((ext_vector_type(4))) _Float16 half4;

__global__ void count_deg_kernel(const int* __restrict__ dst, int* __restrict__ deg, int E) {
    int e = blockIdx.x * blockDim.x + threadIdx.x;
    if (e < E) atomicAdd(&deg[dst[e]], 1);
}

__global__ void block_sum_kernel(const int* __restrict__ deg, int* __restrict__ blockSums, int N) {
    __shared__ int sh[256];
    int i = blockIdx.x * 256 + threadIdx.x;
    int v = (i < N) ? deg[i] : 0;
    sh[threadIdx.x] = v;
    __syncthreads();
    for (int off = 128; off > 0; off >>= 1) {
        if (threadIdx.x < off) sh[threadIdx.x] += sh[threadIdx.x + off];
        __syncthreads();
    }
    if (threadIdx.x == 0) blockSums[blockIdx.x] = sh[0];
}

__global__ void scan_sums_kernel(int* __restrict__ blockSums, int* __restrict__ row_ptr_N, int B) {
    __shared__ int sh[1024];
    int t = threadIdx.x;
    int v = (t < B) ? blockSums[t] : 0;
    sh[t] = v;
    __syncthreads();
    for (int off = 1; off < 1024; off <<= 1) {
        int u = (t >= off) ? sh[t - off] : 0;
        __syncthreads();
        sh[t] += u;
        __syncthreads();
    }
    if (t < B) blockSums[t] = sh[t] - v;
    if (t == 1023) row_ptr_N[0] = sh[1023];
}

__global__ void write_rowptr_kernel(const int* __restrict__ deg, const int* __restrict__ blockOffs,
                                    int* __restrict__ row_ptr, int* __restrict__ cursor, int N) {
    __shared__ int sh[256];
    int i = blockIdx.x * 256 + threadIdx.x;
    int v = (i < N) ? deg[i] : 0;
    sh[threadIdx.x] = v;
    __syncthreads();
    for (int off = 1; off < 256; off <<= 1) {
        int u = (threadIdx.x >= off) ? sh[threadIdx.x - off] : 0;
        __syncthreads();
        sh[threadIdx.x] += u;
        __syncthreads();
    }
    if (i < N) {
        int excl = blockOffs[blockIdx.x] + sh[threadIdx.x] - v;
        row_ptr[i] = excl;
        cursor[i] = excl;
    }
}

__global__ void scatter_kernel(const int* __restrict__ src, const int* __restrict__ dst,
                               int* __restrict__ cursor, unsigned short* __restrict__ src_idx,
                               int E) {
    int e = blockIdx.x * blockDim.x + threadIdx.x;
    if (e < E) {
        int slot = atomicAdd(&cursor[dst[e]], 1);
        src_idx[slot] = (unsigned short)src[e];
    }
}

// Mean aggregation pass 1: fp32 input (x), fp16 output. One wave per node,
// 4 lane-groups x 16 lanes, 4 edges/group in flight.
__global__ void agg_mean_f32in_kernel(const float* __restrict__ h, const int* __restrict__ row_ptr,
                                      const unsigned short* __restrict__ src_idx,
                                      _Float16* __restrict__ h_out, int N) {
    int wid = (blockIdx.x * blockDim.x + threadIdx.x) >> 6;
    int lane = threadIdx.x & 63;
    if (wid >= N) return;
    int beg = row_ptr[wid], end = row_ptr[wid + 1];
    int j = lane >> 4;
    int f = lane & 15;
    float4 a0 = make_float4(0.f, 0.f, 0.f, 0.f);
    float4 a1 = make_float4(0.f, 0.f, 0.f, 0.f);
    float4 a2 = make_float4(0.f, 0.f, 0.f, 0.f);
    float4 a3 = make_float4(0.f, 0.f, 0.f, 0.f);
    for (int e = beg + 4 * j; e < end; e += 16) {
        int rem = end - e;
        int s0 = src_idx[e];
        float4 v0 = *((const float4*)(h + (size_t)s0 * 64) + f);
        a0.x += v0.x; a0.y += v0.y; a0.z += v0.z; a0.w += v0.w;
        if (rem > 1) {
            int s1 = src_idx[e + 1];
            float4 v1 = *((const float4*)(h + (size_t)s1 * 64) + f);
            a1.x += v1.x; a1.y += v1.y; a1.z += v1.z; a1.w += v1.w;
        }
        if (rem > 2) {
            int s2 = src_idx[e + 2];
            float4 v2 = *((const float4*)(h + (size_t)s2 * 64) + f);
            a2.x += v2.x; a2.y += v2.y; a2.z += v2.z; a2.w += v2.w;
        }
        if (rem > 3) {
            int s3 = src_idx[e + 3];
            float4 v3 = *((const float4*)(h + (size_t)s3 * 64) + f);
            a3.x += v3.x; a3.y += v3.y; a3.z += v3.z; a3.w += v3.w;
        }
    }
    a0.x += a1.x + a2.x + a3.x; a0.y += a1.y + a2.y + a3.y;
    a0.z += a1.z + a2.z + a3.z; a0.w += a1.w + a2.w + a3.w;
    a0.x += __shfl_down(a0.x, 32, 64); a0.y += __shfl_down(a0.y, 32, 64);
    a0.z += __shfl_down(a0.z, 32, 64); a0.w += __shfl_down(a0.w, 32, 64);
    a0.x += __shfl_down(a0.x, 16, 64); a0.y += __shfl_down(a0.y, 16, 64);
    a0.z += __shfl_down(a0.z, 16, 64); a0.w += __shfl_down(a0.w, 16, 64);
    if (lane < 16) {
        int d = end - beg;
        float inv = d > 0 ? 1.f / (float)d : 0.f;
        half4 o;
        o.x = (_Float16)(a0.x * inv); o.y = (_Float16)(a0.y * inv);
        o.z = (_Float16)(a0.z * inv); o.w = (_Float16)(a0.w * inv);
        *((half4*)(h_out + (size_t)wid * 64) + lane) = o;
    }
}

// Mean aggregation passes 2-3: fp16 in/out.
__global__ void agg_mean_f16_kernel(const _Float16* __restrict__ h, const int* __restrict__ row_ptr,
                                    const unsigned short* __restrict__ src_idx,
                                    _Float16* __restrict__ h_out, int N) {
    int wid = (blockIdx.x * blockDim.x + threadIdx.x) >> 6;
    int lane = threadIdx.x & 63;
    if (wid >= N) return;
    int beg = row_ptr[wid], end = row_ptr[wid + 1];
    int j = lane >> 4;
    int f = lane & 15;
    float4 a0 = make_float4(0.f, 0.f, 0.f, 0.f);
    float4 a1 = make_float4(0.f, 0.f, 0.f, 0.f);
    float4 a2 = make_float4(0.f, 0.f, 0.f, 0.f);
    float4 a3 = make_float4(0.f, 0.f, 0.f, 0.f);
    for (int e = beg + 4 * j; e < end; e += 16) {
        int rem = end - e;
        int s0 = src_idx[e];
        half4 v0 = *((const half4*)(h + (size_t)s0 * 64) + f);
        a0.x += (float)v0.x; a0.y += (float)v0.y; a0.z += (float)v0.z; a0.w += (float)v0.w;
        if (rem > 1) {
            int s1 = src_idx[e + 1];
            half4 v1 = *((const half4*)(h + (size_t)s1 * 64) + f);
            a1.x += (float)v1.x; a1.y += (float)v1.y; a1.z += (float)v1.z; a1.w += (float)v1.w;
        }
        if (rem > 2) {
            int s2 = src_idx[e + 2];
            half4 v2 = *((const half4*)(h + (size_t)s2 * 64) + f);
            a2.x += (float)v2.x; a2.y += (float)v2.y; a2.z += (float)v2.z; a2.w += (float)v2.w;
        }
        if (rem > 3) {
            int s3 = src_idx[e + 3];
            half4 v3 = *((const half4*)(h + (size_t)s3 * 64) + f);
            a3.x += (float)v3.x; a3.y += (float)v3.y; a3.z += (float)v3.z; a3.w += (float)v3.w;
        }
    }
    a0.x += a1.x + a2.x + a3.x; a0.y += a1.y + a2.y + a3.y;
    a0.z += a1.z + a2.z + a3.z; a0.w += a1.w + a2.w + a3.w;
    a0.x += __shfl_down(a0.x, 32, 64); a0.y += __shfl_down(a0.y, 32, 64);
    a0.z += __shfl_down(a0.z, 32, 64); a0.w += __shfl_down(a0.w, 32, 64);
    a0.x += __shfl_down(a0.x, 16, 64); a0.y += __shfl_down(a0.y, 16, 64);
    a0.z += __shfl_down(a0.z, 16, 64); a0.w += __shfl_down(a0.w, 16, 64);
    if (lane < 16) {
        int d = end - beg;
        float inv = d > 0 ? 1.f / (float)d : 0.f;
        half4 o;
        o.x = (_Float16)(a0.x * inv); o.y = (_Float16)(a0.y * inv);
        o.z = (_Float16)(a0.z * inv); o.w = (_Float16)(a0.w * inv);
        *((half4*)(h_out + (size_t)wid * 64) + lane) = o;
    }
}

// Conv1 transform: xs = (x+h1+h2+h3)/4 (h's fp16). z1 = xs@W_lin1 -> fp16.
__global__ void xform1_kernel(const float* __restrict__ x, const _Float16* __restrict__ hA,
                              const _Float16* __restrict__ hB, const _Float16* __restrict__ hC,
                              const float* __restrict__ W_lin1, const float* __restrict__ W_att1,
                              _Float16* __restrict__ z1, float* __restrict__ a1,
                              float* __restrict__ a2, int N) {
    __shared__ float row[4][64];
    int wib = threadIdx.x >> 6;
    int lane = threadIdx.x & 63;
    int n = blockIdx.x * 4 + wib;
    int nc = n < N ? n : N - 1;
    size_t idx = (size_t)nc * 64 + lane;
    float xv = (x[idx] + (float)hA[idx] + (float)hB[idx] + (float)hC[idx]) * 0.25f;
    row[wib][lane] = xv;
    __syncthreads();
    float p1 = xv * W_att1[lane];
    float p2 = xv * W_att1[64 + lane];
    for (int off = 32; off > 0; off >>= 1) {
        p1 += __shfl_down(p1, off, 64);
        p2 += __shfl_down(p2, off, 64);
    }
    float acc = 0.f;
    #pragma unroll
    for (int k = 0; k < 64; ++k) acc += row[wib][k] * W_lin1[k * 64 + lane];
    if (n < N) {
        z1[(size_t)n * 64 + lane] = (_Float16)acc;
        if (lane == 0) { a1[n] = p1; a2[n] = p2; }
    }
}

__global__ void xform2_kernel(const float* __restrict__ h1, const float* __restrict__ W_lin2,
                              const float* __restrict__ W_att2,
                              float* __restrict__ z2, float* __restrict__ a1, float* __restrict__ a2,
                              int N) {
    __shared__ float row[4][64];
    int wib = threadIdx.x >> 6;
    int lane = threadIdx.x & 63;
    int n = blockIdx.x * 4 + wib;
    int nc = n < N ? n : N - 1;
    float hv = h1[(size_t)nc * 64 + lane];
    row[wib][lane] = hv;
    __syncthreads();
    float p1 = hv * W_att2[lane];
    float p2 = hv * W_att2[64 + lane];
    for (int off = 32; off > 0; off >>= 1) {
        p1 += __shfl_down(p1, off, 64);
        p2 += __shfl_down(p2, off, 64);
    }
    float acc = 0.f;
    if (lane < 32) {
        #pragma unroll
        for (int k = 0; k < 64; ++k) acc += row[wib][k] * W_lin2[k * 32 + lane];
    }
    if (n < N) {
        if (lane < 32) z2[(size_t)n * 32 + lane] = acc;
        if (lane == 0) { a1[n] = p1; a2[n] = p2; }
    }
}

// Conv1 aggregation (D=64): fp16 z gather, fp32 accumulate, relu -> fp32 out.
__global__ void agg_conv64_kernel(const _Float16* __restrict__ z, const float* __restrict__ a1v,
                                  const float* __restrict__ a2v, const float* __restrict__ b_att,
                                  const int* __restrict__ row_ptr,
                                  const unsigned short* __restrict__ src_idx,
                                  float* __restrict__ outp, int N) {
    int wid = (blockIdx.x * blockDim.x + threadIdx.x) >> 6;
    int lane = threadIdx.x & 63;
    if (wid >= N) return;
    float ad = a2v[wid] + b_att[0];
    int beg = row_ptr[wid], end = row_ptr[wid + 1];
    int j = lane >> 4;
    int f = lane & 15;
    float4 a0 = make_float4(0.f, 0.f, 0.f, 0.f);
    float4 a1 = make_float4(0.f, 0.f, 0.f, 0.f);
    float4 a2 = make_float4(0.f, 0.f, 0.f, 0.f);
    float4 a3 = make_float4(0.f, 0.f, 0.f, 0.f);
    for (int e = beg + 4 * j; e < end; e += 16) {
        int rem = end - e;
        int s0 = src_idx[e];
        float sc0 = a1v[s0] + ad; sc0 = sc0 > 0.f ? sc0 : 0.01f * sc0;
        half4 v0 = *((const half4*)(z + (size_t)s0 * 64) + f);
        a0.x += sc0 * (float)v0.x; a0.y += sc0 * (float)v0.y;
        a0.z += sc0 * (float)v0.z; a0.w += sc0 * (float)v0.w;
        if (rem > 1) {
            int s1 = src_idx[e + 1];
            float sc1 = a1v[s1] + ad; sc1 = sc1 > 0.f ? sc1 : 0.01f * sc1;
            half4 v1 = *((const half4*)(z + (size_t)s1 * 64) + f);
            a1.x += sc1 * (float)v1.x; a1.y += sc1 * (float)v1.y;
            a1.z += sc1 * (float)v1.z; a1.w += sc1 * (float)v1.w;
        }
        if (rem > 2) {
            int s2 = src_idx[e + 2];
            float sc2 = a1v[s2] + ad; sc2 = sc2 > 0.f ? sc2 : 0.01f * sc2;
            half4 v2 = *((const half4*)(z + (size_t)s2 * 64) + f);
            a2.x += sc2 * (float)v2.x; a2.y += sc2 * (float)v2.y;
            a2.z += sc2 * (float)v2.z; a2.w += sc2 * (float)v2.w;
        }
        if (rem > 3) {
            int s3 = src_idx[e + 3];
            float sc3 = a1v[s3] + ad; sc3 = sc3 > 0.f ? sc3 : 0.01f * sc3;
            half4 v3 = *((const half4*)(z + (size_t)s3 * 64) + f);
            a3.x += sc3 * (float)v3.x; a3.y += sc3 * (float)v3.y;
            a3.z += sc3 * (float)v3.z; a3.w += sc3 * (float)v3.w;
        }
    }
    a0.x += a1.x + a2.x + a3.x; a0.y += a1.y + a2.y + a3.y;
    a0.z += a1.z + a2.z + a3.z; a0.w += a1.w + a2.w + a3.w;
    a0.x += __shfl_down(a0.x, 32, 64); a0.y += __shfl_down(a0.y, 32, 64);
    a0.z += __shfl_down(a0.z, 32, 64); a0.w += __shfl_down(a0.w, 32, 64);
    a0.x += __shfl_down(a0.x, 16, 64); a0.y += __shfl_down(a0.y, 16, 64);
    a0.z += __shfl_down(a0.z, 16, 64); a0.w += __shfl_down(a0.w, 16, 64);
    if (lane < 16) {
        float4 o;
        o.x = fmaxf(a0.x, 0.f); o.y = fmaxf(a0.y, 0.f);
        o.z = fmaxf(a0.z, 0.f); o.w = fmaxf(a0.w, 0.f);
        *((float4*)(outp + (size_t)wid * 64) + lane) = o;
    }
}

// Conv2 aggregation (D=32): fp32 z2 (output-path precision), fp32 out.
__global__ void agg_conv32_kernel(const float* __restrict__ z, const float* __restrict__ a1v,
                                  const float* __restrict__ a2v, const float* __restrict__ b_att,
                                  const int* __restrict__ row_ptr,
                                  const unsigned short* __restrict__ src_idx,
                                  float* __restrict__ outp, int N) {
    int wid = (blockIdx.x * blockDim.x + threadIdx.x) >> 6;
    int lane = threadIdx.x & 63;
    if (wid >= N) return;
    float ad = a2v[wid] + b_att[0];
    int beg = row_ptr[wid], end = row_ptr[wid + 1];
    int j = lane >> 3;
    int f = lane & 7;
    float4 a0 = make_float4(0.f, 0.f, 0.f, 0.f);
    float4 a1 = make_float4(0.f, 0.f, 0.f, 0.f);
    for (int e = beg + 2 * j; e < end; e += 16) {
        int s0 = src_idx[e];
        float sc0 = a1v[s0] + ad; sc0 = sc0 > 0.f ? sc0 : 0.01f * sc0;
        float4 v0 = *((const float4*)(z + (size_t)s0 * 32) + f);
        a0.x += sc0 * v0.x; a0.y += sc0 * v0.y; a0.z += sc0 * v0.z; a0.w += sc0 * v0.w;
        if (e + 1 < end) {
            int s1 = src_idx[e + 1];
            float sc1 = a1v[s1] + ad; sc1 = sc1 > 0.f ? sc1 : 0.01f * sc1;
            float4 v1 = *((const float4*)(z + (size_t)s1 * 32) + f);
            a1.x += sc1 * v1.x; a1.y += sc1 * v1.y; a1.z += sc1 * v1.z; a1.w += sc1 * v1.w;
        }
    }
    a0.x += a1.x; a0.y += a1.y; a0.z += a1.z; a0.w += a1.w;
    a0.x += __shfl_down(a0.x, 32, 64); a0.y += __shfl_down(a0.y, 32, 64);
    a0.z += __shfl_down(a0.z, 32, 64); a0.w += __shfl_down(a0.w, 32, 64);
    a0.x += __shfl_down(a0.x, 16, 64); a0.y += __shfl_down(a0.y, 16, 64);
    a0.z += __shfl_down(a0.z, 16, 64); a0.w += __shfl_down(a0.w, 16, 64);
    a0.x += __shfl_down(a0.x, 8, 64);  a0.y += __shfl_down(a0.y, 8, 64);
    a0.z += __shfl_down(a0.z, 8, 64);  a0.w += __shfl_down(a0.w, 8, 64);
    if (lane < 8) {
        *((float4*)(outp + (size_t)wid * 32) + lane) = a0;
    }
}

extern "C" void kernel_launch(void* const* d_in, const int* in_sizes, int n_in,
                              void* d_out, int out_size, void* d_ws, size_t ws_size,
                              hipStream_t stream) {
    const float* x      = (const float*)d_in[0];
    const int*   ei     = (const int*)d_in[1];
    const float* W_att1 = (const float*)d_in[2];
    const float* b_att1 = (const float*)d_in[3];
    const float* W_lin1 = (const float*)d_in[4];
    const float* W_att2 = (const float*)d_in[5];
    const float* b_att2 = (const float*)d_in[6];
    const float* W_lin2 = (const float*)d_in[7];
    float* out = (float*)d_out;

    int N = in_sizes[0] / 64;   // 50000 (< 65536, required for u16 src_idx)
    int E = in_sizes[1] / 2;
    const int* src = ei;
    const int* dst = ei + E;

    char* ws = (char*)d_ws;
    size_t off = 0;
    auto alloc = [&](size_t bytes) -> void* {
        void* p = ws + off;
        off += (bytes + 255) & ~(size_t)255;
        return p;
    };
    int*            deg       = (int*)alloc((size_t)N * 4);
    int*            row_ptr   = (int*)alloc((size_t)(N + 1) * 4);
    int*            cursor    = (int*)alloc((size_t)N * 4);
    unsigned short* src_idx   = (unsigned short*)alloc((size_t)E * 2);
    int*            blockSums = (int*)alloc((size_t)1024 * 4);
    _Float16* hA = (_Float16*)alloc((size_t)N * 64 * 2);   // h1 (smoothing)
    _Float16* hB = (_Float16*)alloc((size_t)N * 64 * 2);   // h2
    _Float16* hC = (_Float16*)alloc((size_t)N * 64 * 2);   // h3
    _Float16* z1 = (_Float16*)alloc((size_t)N * 64 * 2);   // conv1 lin output
    float* h1c = (float*)alloc((size_t)N * 64 * 4);        // relu(conv1 feats)
    float* z2  = (float*)alloc((size_t)N * 32 * 4);        // conv2 lin output
    float* a1  = (float*)alloc((size_t)N * 4);
    float* a2  = (float*)alloc((size_t)N * 4);
    float* a1b = (float*)alloc((size_t)N * 4);
    float* a2b = (float*)alloc((size_t)N * 4);

    const int tb = 256;
    hipMemsetAsync(deg, 0, (size_t)N * 4, stream);
    count_deg_kernel<<<(E + tb - 1) / tb, tb, 0, stream>>>(dst, deg, E);

    int B = (N + 255) / 256;
    block_sum_kernel<<<B, 256, 0, stream>>>(deg, blockSums, N);
    scan_sums_kernel<<<1, 1024, 0, stream>>>(blockSums, row_ptr + N, B);
    write_rowptr_kernel<<<B, 256, 0, stream>>>(deg, blockSums, row_ptr, cursor, N);

    scatter_kernel<<<(E + tb - 1) / tb, tb, 0, stream>>>(src, dst, cursor, src_idx, E);

    int aggBlocks = (N * 64 + tb - 1) / tb;   // one wave per node
    agg_mean_f32in_kernel<<<aggBlocks, tb, 0, stream>>>(x,  row_ptr, src_idx, hA, N);
    agg_mean_f16_kernel<<<aggBlocks, tb, 0, stream>>>(hA, row_ptr, src_idx, hB, N);
    agg_mean_f16_kernel<<<aggBlocks, tb, 0, stream>>>(hB, row_ptr, src_idx, hC, N);

    int xfBlocks = (N + 3) / 4;
    xform1_kernel<<<xfBlocks, 256, 0, stream>>>(x, hA, hB, hC, W_lin1, W_att1,
                                                z1, a1, a2, N);
    agg_conv64_kernel<<<aggBlocks, tb, 0, stream>>>(z1, a1, a2, b_att1, row_ptr, src_idx,
                                                    h1c, N);
    xform2_kernel<<<xfBlocks, 256, 0, stream>>>(h1c, W_lin2, W_att2, z2, a1b, a2b, N);
    agg_conv32_kernel<<<aggBlocks, tb, 0, stream>>>(z2, a1b, a2b, b_att2, row_ptr, src_idx,
                                                    out, N);
}